// Round 20
// baseline (274.101 us; speedup 1.0000x reference)
//
#include <hip/hip_runtime.h>

typedef _Float16 f16;
typedef _Float16 f16x2 __attribute__((ext_vector_type(2)));
typedef _Float16 f16x8 __attribute__((ext_vector_type(8)));
typedef float f32x4 __attribute__((ext_vector_type(4)));

namespace {

constexpr int kC = 16, kN = 8192, kH = 181, kOut = 3;
constexpr int kMB = 64;            // points per block (4-tile B-hold)
constexpr int kKpad = 384;         // 12 ksteps * 32
constexpr int kNT = 48;            // tiles of 16 output-comps (4 neurons each)
constexpr int kKS = 12;            // k-steps of 32
constexpr int kRowB = 784;         // 768 data bytes + 16B pad (bank spread)
constexpr float kOmega = 30.f, kS2 = 100.f;

constexpr size_t kWLayerStride = (size_t)kNT * kKS * 64 * 8;  // f16 per (c,layer)
constexpr size_t kWfOff = kWLayerStride * kC * 2;             // f16 elems
constexpr size_t kWfStride = (size_t)kKS * 64 * 8;
constexpr size_t kW0Off = kWfOff + (size_t)kC * kWfStride;    // layer-0 frags
constexpr size_t kW0Stride = (size_t)kNT * 64 * 8;            // per c

__device__ __forceinline__ int xadr(int row, int colb) { return row * kRowB + colb; }

// ---- prep: pack hidden-layer complex weights into fp16 fragment order
// ws[c][L][nt][ks][lane][8]; K rows 2i/2i+1 = (x_re,x_im), 16-wide tile dim =
// 4o+comp. Used as the MFMA *A* operand (C^T formulation).
__global__ __launch_bounds__(768) void prep_hidden(
    const int* __restrict__ model_idx,
    const float* __restrict__ W1a, const float* __restrict__ W1b,
    const float* __restrict__ W2a, const float* __restrict__ W2b,
    f16* __restrict__ ws)
{
  __shared__ float s[kH][2][4][2];   // [i][branch][o_sub][reim]
  const int bid = blockIdx.x;
  const int c  = bid / (2 * kNT);
  const int L  = (bid / kNT) % 2;
  const int nt = bid % kNT;
  const int m  = model_idx[c];
  const float* Wa = (L == 0 ? W1a : W2a) + (size_t)m * kH * kH * 2;
  const float* Wb = (L == 0 ? W1b : W2b) + (size_t)m * kH * kH * 2;
  const int t = threadIdx.x;
  if (t < 2 * kH) {
    const int i = t >> 1, br = t & 1;
    const float* src = (br ? Wb : Wa) + ((size_t)i * kH + nt * 4) * 2;
#pragma unroll
    for (int e = 0; e < 8; ++e) {
      const int osub = e >> 1, reim = e & 1;
      s[i][br][osub][reim] = (nt * 4 + osub < kH) ? src[osub * 2 + reim] : 0.f;
    }
  }
  __syncthreads();
  const int ks = t >> 6, lane = t & 63;
  const int kg = lane >> 4, l15 = lane & 15;
  const int osub = l15 >> 2, comp = l15 & 3, br = comp >> 1;
  const int o = nt * 4 + osub;
  f16x8 v;
#pragma unroll
  for (int j = 0; j < 8; ++j) {
    const int k = ks * 32 + kg * 8 + j;
    float f = 0.f;
    if (k < 2 * kH && o < kH) {
      const int i = k >> 1, kodd = k & 1;
      const int reim = kodd ? (1 - (comp & 1)) : (comp & 1);
      f = s[i][br][osub][reim];
      if (kodd && !(comp & 1)) f = -f;   // -w_im for real-output rows
    }
    v[j] = (f16)f;
  }
  *(f16x8*)&ws[(((size_t)(c * 2 + L) * kNT + nt) * kKS + ks) * 512 + lane * 8] = v;
}

// ---- prep: final layer (real part): col j<3, k=2i -> wf_re, 2i+1 -> -wf_im
__global__ __launch_bounds__(768) void prep_final(
    const int* __restrict__ model_idx, const float* __restrict__ Wf,
    f16* __restrict__ ws)
{
  const int c = blockIdx.x;
  const int m = model_idx[c];
  const int t = threadIdx.x;
  const int ks = t >> 6, lane = t & 63;
  const int kg = lane >> 4, col = lane & 15;
  f16x8 v;
#pragma unroll
  for (int j = 0; j < 8; ++j) {
    const int k = ks * 32 + kg * 8 + j;
    float f = 0.f;
    if (k < 2 * kH && col < kOut) {
      const int i = k >> 1;
      const float* p = &Wf[(((size_t)m * kH + i) * kOut + col) * 2];
      f = (k & 1) ? -p[1] : p[0];
    }
    v[j] = (f16)f;
  }
  *(f16x8*)&ws[kWfOff + ((size_t)c * kKS + ks) * 512 + lane * 8] = v;
}

// ---- prep: layer-0 A-frags. One K=32 tile, only k=0,1 valid.
// comp rows: (W0a[k][o], 0, W0b[k][o], 0) -> acc = (la, 0, lb, 0).
__global__ __launch_bounds__(256) void prep_l0(
    const int* __restrict__ model_idx,
    const float* __restrict__ W0a, const float* __restrict__ W0b,
    f16* __restrict__ ws)
{
  const int c = blockIdx.x;
  const int m = model_idx[c];
#pragma unroll 1
  for (int it = 0; it < 12; ++it) {
    const int slot = it * 256 + threadIdx.x;   // 48 nt x 64 lanes
    const int nt = slot >> 6, lane = slot & 63;
    const int kg = lane >> 4, l15 = lane & 15;
    const int osub = l15 >> 2, comp = l15 & 3;
    const int o = nt * 4 + osub;
    f16x8 v = {};
    if (kg == 0 && o < kH && (comp & 1) == 0) {
#pragma unroll
      for (int k = 0; k < 2; ++k) {
        const float f = (comp == 0) ? W0a[(m * 2 + k) * kH + o]
                                    : W0b[(m * 2 + k) * kH + o];
        v[k] = (f16)f;
      }
    }
    *(f16x8*)&ws[kW0Off + (size_t)c * kW0Stride + (size_t)slot * 8] = v;
  }
}

// one Gabor activation (lane-local) writing f16x2 to X
__device__ __forceinline__ void gabor_store(
    char* __restrict__ X, const f32x4& a,
    float br_, float bi_, float cr_, float ci_, int row, int q)
{
  const float v0 = a[0] + br_, v1 = a[1] + bi_;
  const float v2 = a[2] + cr_, v3 = a[3] + ci_;
  const float mag = kS2 * (v0 * v0 + v1 * v1 + v2 * v2 + v3 * v3);
  const float amp = __expf(fmaf(-kOmega, v1, -mag));
  const float ph  = kOmega * v0;
  f16x2 pv = {(f16)(amp * __cosf(ph)), (f16)(amp * __sinf(ph))};
  *(f16x2*)(X + xadr(row, q * 4)) = pv;
}

// ---- one hidden layer, IN PLACE, C^T, P=64, quarter-window A pipeline with
// ONE-MI-DEEP DEFERRED ACTIVATION. r19 baseline plus two latency fixes:
//  - bias load at TOP of mi body (r19 had it just before use -> ~200cyc
//    exposed L2 latency 24x per wave per layer),
//  - activation of mi-1 split into 4 chunks, one per quarter, placed between
//    that quarter's load-issue and its MFMA cluster: the VALU chunk executes
//    inside the quarter's vmcnt-wait window instead of serially after Q3.
// State carried in statically-indexed regs (accP[4], biasP, qP; 16 v_mov/mi
// copy ~2% overhead). sched_barrier(0) pins load|act|MFMA order per quarter.
__device__ __forceinline__ void hidden_gemm(
    char* __restrict__ X, const f16x8* __restrict__ wl,
    const float* __restrict__ ba, const float* __restrict__ bb,
    int w, int lane)
{
  const int kg = lane >> 4, l15 = lane & 15;
  f16x8 B[4][kKS];
#pragma unroll
  for (int pt = 0; pt < 4; ++pt)
#pragma unroll
    for (int ks = 0; ks < kKS; ++ks)
      B[pt][ks] = *(const f16x8*)(X + xadr(l15 + 16 * pt, ks * 64 + kg * 16));
  __syncthreads();   // all waves hold X in regs; X may now be overwritten

  f16x8 A0[3], A1[3];
  {  // prologue: first quarter of mi=0
    const f16x8* ap0 = wl + (size_t)(w * 12) * (kKS * 64) + lane;
#pragma unroll
    for (int j = 0; j < 3; ++j) A0[j] = ap0[j * 64];
  }

  f32x4 accP[4];
  float brP = 0.f, biP = 0.f, crP = 0.f, ciP = 0.f;
  int qP = 0;

#pragma unroll 1
  for (int mi = 0; mi < 12; ++mi) {
    const int nt = w * 12 + mi;
    const int q = nt * 4 + kg;           // this lane's neuron
    const f16x8* ap = wl + (size_t)nt * (kKS * 64) + lane;
    // bias load EARLY: lands while the 4 quarters run
    float br_ = 0.f, bi_ = 0.f, cr_ = 0.f, ci_ = 0.f;
    if (q < kH) {
      const float2 bav = *(const float2*)&ba[q * 2];
      const float2 bbv = *(const float2*)&bb[q * 2];
      br_ = bav.x; bi_ = bav.y; cr_ = bbv.x; ci_ = bbv.y;
    }
    f32x4 acc[4] = {};
    // Q0: issue ks3-5 | act(prev pt0) | MFMA ks0-2
#pragma unroll
    for (int j = 0; j < 3; ++j) A1[j] = ap[(3 + j) * 64];
    __builtin_amdgcn_sched_barrier(0);
    if (mi > 0) gabor_store(X, accP[0], brP, biP, crP, ciP, l15, qP);
    __builtin_amdgcn_sched_barrier(0);
    __builtin_amdgcn_s_setprio(1);
#pragma unroll
    for (int ks = 0; ks < 3; ++ks) {
      acc[0] = __builtin_amdgcn_mfma_f32_16x16x32_f16(A0[ks], B[0][ks], acc[0], 0, 0, 0);
      acc[1] = __builtin_amdgcn_mfma_f32_16x16x32_f16(A0[ks], B[1][ks], acc[1], 0, 0, 0);
      acc[2] = __builtin_amdgcn_mfma_f32_16x16x32_f16(A0[ks], B[2][ks], acc[2], 0, 0, 0);
      acc[3] = __builtin_amdgcn_mfma_f32_16x16x32_f16(A0[ks], B[3][ks], acc[3], 0, 0, 0);
    }
    __builtin_amdgcn_s_setprio(0);
    __builtin_amdgcn_sched_barrier(0);
    // Q1: issue ks6-8 | act(prev pt1) | MFMA ks3-5
#pragma unroll
    for (int j = 0; j < 3; ++j) A0[j] = ap[(6 + j) * 64];
    __builtin_amdgcn_sched_barrier(0);
    if (mi > 0) gabor_store(X, accP[1], brP, biP, crP, ciP, l15 + 16, qP);
    __builtin_amdgcn_sched_barrier(0);
    __builtin_amdgcn_s_setprio(1);
#pragma unroll
    for (int ks = 0; ks < 3; ++ks) {
      acc[0] = __builtin_amdgcn_mfma_f32_16x16x32_f16(A1[ks], B[0][3 + ks], acc[0], 0, 0, 0);
      acc[1] = __builtin_amdgcn_mfma_f32_16x16x32_f16(A1[ks], B[1][3 + ks], acc[1], 0, 0, 0);
      acc[2] = __builtin_amdgcn_mfma_f32_16x16x32_f16(A1[ks], B[2][3 + ks], acc[2], 0, 0, 0);
      acc[3] = __builtin_amdgcn_mfma_f32_16x16x32_f16(A1[ks], B[3][3 + ks], acc[3], 0, 0, 0);
    }
    __builtin_amdgcn_s_setprio(0);
    __builtin_amdgcn_sched_barrier(0);
    // Q2: issue ks9-11 | act(prev pt2) | MFMA ks6-8
#pragma unroll
    for (int j = 0; j < 3; ++j) A1[j] = ap[(9 + j) * 64];
    __builtin_amdgcn_sched_barrier(0);
    if (mi > 0) gabor_store(X, accP[2], brP, biP, crP, ciP, l15 + 32, qP);
    __builtin_amdgcn_sched_barrier(0);
    __builtin_amdgcn_s_setprio(1);
#pragma unroll
    for (int ks = 0; ks < 3; ++ks) {
      acc[0] = __builtin_amdgcn_mfma_f32_16x16x32_f16(A0[ks], B[0][6 + ks], acc[0], 0, 0, 0);
      acc[1] = __builtin_amdgcn_mfma_f32_16x16x32_f16(A0[ks], B[1][6 + ks], acc[1], 0, 0, 0);
      acc[2] = __builtin_amdgcn_mfma_f32_16x16x32_f16(A0[ks], B[2][6 + ks], acc[2], 0, 0, 0);
      acc[3] = __builtin_amdgcn_mfma_f32_16x16x32_f16(A0[ks], B[3][6 + ks], acc[3], 0, 0, 0);
    }
    __builtin_amdgcn_s_setprio(0);
    __builtin_amdgcn_sched_barrier(0);
    // Q3: issue next-mi ks0-2 | act(prev pt3) | MFMA ks9-11
#pragma unroll
    for (int j = 0; j < 3; ++j) A0[j] = ap[(kKS + j) * 64];
    __builtin_amdgcn_sched_barrier(0);
    if (mi > 0) gabor_store(X, accP[3], brP, biP, crP, ciP, l15 + 48, qP);
    __builtin_amdgcn_sched_barrier(0);
    __builtin_amdgcn_s_setprio(1);
#pragma unroll
    for (int ks = 0; ks < 3; ++ks) {
      acc[0] = __builtin_amdgcn_mfma_f32_16x16x32_f16(A1[ks], B[0][9 + ks], acc[0], 0, 0, 0);
      acc[1] = __builtin_amdgcn_mfma_f32_16x16x32_f16(A1[ks], B[1][9 + ks], acc[1], 0, 0, 0);
      acc[2] = __builtin_amdgcn_mfma_f32_16x16x32_f16(A1[ks], B[2][9 + ks], acc[2], 0, 0, 0);
      acc[3] = __builtin_amdgcn_mfma_f32_16x16x32_f16(A1[ks], B[3][9 + ks], acc[3], 0, 0, 0);
    }
    __builtin_amdgcn_s_setprio(0);
    // carry state to next mi (static indices; ~16 v_mov = 2% overhead)
#pragma unroll
    for (int pt = 0; pt < 4; ++pt) accP[pt] = acc[pt];
    brP = br_; biP = bi_; crP = cr_; ciP = ci_; qP = q;
  }
  // epilogue: activation of mi=11
  gabor_store(X, accP[0], brP, biP, crP, ciP, l15,      qP);
  gabor_store(X, accP[1], brP, biP, crP, ciP, l15 + 16, qP);
  gabor_store(X, accP[2], brP, biP, crP, ciP, l15 + 32, qP);
  gabor_store(X, accP[3], brP, biP, crP, ciP, l15 + 48, qP);
}

__global__ __launch_bounds__(256, 2)   // B 192 (AGPR) + windows 24 + 2x acc 32
void wire_main(
    const float* __restrict__ inp, const int* __restrict__ indices,
    const int* __restrict__ model_idx, const int* __restrict__ bias_idx,
    const float* __restrict__ b0a, const float* __restrict__ b0b,
    const float* __restrict__ b1a, const float* __restrict__ b1b,
    const float* __restrict__ b2a, const float* __restrict__ b2b,
    const float* __restrict__ bf, const f16* __restrict__ wsW,
    float* __restrict__ out)
{
  __shared__ __align__(16) char X[kMB * kRowB];   // 49 KB single buffer
  const int d = blockIdx.x;
  const int lg = (d & 7) * 256 + (d >> 3);   // XCD swizzle (2048 % 8 == 0)
  const int c = lg >> 7;                     // 128 blocks per c
  const int n0 = (lg & 127) * kMB;
  const int src = indices[c], m = model_idx[c], bix = bias_idx[c];
  const int tid = threadIdx.x, w = tid >> 6, lane = tid & 63;
  const int kg = lane >> 4, l15 = lane & 15;

  // ---- layer 0 as MFMA (C^T): B = input coords (k=0,1 of one K-tile),
  // A = packed W0 frags; unified Gabor activation with v1=v3=0.
  {
    f16x8 Bx[4];
#pragma unroll
    for (int pt = 0; pt < 4; ++pt) {
      const int row = l15 + 16 * pt;
      const float2 xv = *(const float2*)&inp[((size_t)src * kN + n0 + row) * 2];
      f16x8 b = {};
      if (kg == 0) { b[0] = (f16)xv.x; b[1] = (f16)xv.y; }
      Bx[pt] = b;
    }
    const f16x8* w0p = (const f16x8*)(wsW + kW0Off + (size_t)c * kW0Stride);
    const float* b0av = b0a + (size_t)bix * kH;
    const float* b0bv = b0b + (size_t)bix * kH;
#pragma unroll 1
    for (int mi = 0; mi < 12; ++mi) {
      const int nt = w * 12 + mi;
      const int q = nt * 4 + kg;
      float br_ = 0.f, cr_ = 0.f;
      if (q < kH) { br_ = b0av[q]; cr_ = b0bv[q]; }
      const f16x8 a = w0p[nt * 64 + lane];
      f32x4 acc[4] = {};
      __builtin_amdgcn_s_setprio(1);
      acc[0] = __builtin_amdgcn_mfma_f32_16x16x32_f16(a, Bx[0], acc[0], 0, 0, 0);
      acc[1] = __builtin_amdgcn_mfma_f32_16x16x32_f16(a, Bx[1], acc[1], 0, 0, 0);
      acc[2] = __builtin_amdgcn_mfma_f32_16x16x32_f16(a, Bx[2], acc[2], 0, 0, 0);
      acc[3] = __builtin_amdgcn_mfma_f32_16x16x32_f16(a, Bx[3], acc[3], 0, 0, 0);
      __builtin_amdgcn_s_setprio(0);
#pragma unroll
      for (int pt = 0; pt < 4; ++pt) {
        const float v0 = acc[pt][0] + br_;
        const float v2 = acc[pt][2] + cr_;
        const float mag = kS2 * (v0 * v0 + v2 * v2);
        const float amp = __expf(-mag);
        const float ph  = kOmega * v0;
        f16x2 pv = {(f16)(amp * __cosf(ph)), (f16)(amp * __sinf(ph))};
        *(f16x2*)(&X[0] + xadr(l15 + 16 * pt, q * 4)) = pv;
      }
    }
  }
  __syncthreads();
  hidden_gemm(X, (const f16x8*)(wsW + (size_t)(c * 2 + 0) * kWLayerStride),
              b1a + (size_t)bix * kH * 2, b1b + (size_t)bix * kH * 2, w, lane);
  __syncthreads();
  hidden_gemm(X, (const f16x8*)(wsW + (size_t)(c * 2 + 1) * kWLayerStride),
              b2a + (size_t)bix * kH * 2, b2b + (size_t)bix * kH * 2, w, lane);
  __syncthreads();
  // ---- final complex 181->3, real part; wave w owns point-tile w
  {
    const f16x8* wf = (const f16x8*)(wsW + kWfOff + (size_t)c * kWfStride);
    f32x4 facc = {0.f, 0.f, 0.f, 0.f};
#pragma unroll
    for (int ks = 0; ks < kKS; ++ks) {
      f16x8 a = *(const f16x8*)(&X[0] + xadr(l15 + 16 * w, ks * 64 + kg * 16));
      f16x8 b = wf[(size_t)ks * 64 + lane];
      facc = __builtin_amdgcn_mfma_f32_16x16x32_f16(a, b, facc, 0, 0, 0);
    }
    if (l15 < kOut) {
      const float bfr = bf[(bix * kOut + l15) * 2];
#pragma unroll
      for (int j = 0; j < 4; ++j) {
        const int row = w * 16 + kg * 4 + j;
        out[((size_t)c * kN + n0 + row) * kOut + l15] = facc[j] + bfr;
      }
    }
  }
}

}  // namespace

extern "C" void kernel_launch(void* const* d_in, const int* in_sizes, int n_in,
                              void* d_out, int out_size, void* d_ws, size_t ws_size,
                              hipStream_t stream) {
  const float* inp       = (const float*)d_in[0];
  const int*   indices   = (const int*)  d_in[1];
  const int*   model_idx = (const int*)  d_in[2];
  const int*   bias_idx  = (const int*)  d_in[3];
  const float* W0a = (const float*)d_in[4];
  const float* b0a = (const float*)d_in[5];
  const float* W0b = (const float*)d_in[6];
  const float* b0b = (const float*)d_in[7];
  const float* W1a = (const float*)d_in[8];
  const float* b1a = (const float*)d_in[9];
  const float* W1b = (const float*)d_in[10];
  const float* b1b = (const float*)d_in[11];
  const float* W2a = (const float*)d_in[12];
  const float* b2a = (const float*)d_in[13];
  const float* W2b = (const float*)d_in[14];
  const float* b2b = (const float*)d_in[15];
  const float* Wf  = (const float*)d_in[16];
  const float* bff = (const float*)d_in[17];
  f16*   ws  = (f16*)d_ws;     // needs ~19.9 MB
  float* out = (float*)d_out;

  prep_hidden<<<dim3(kC * 2 * kNT), dim3(768), 0, stream>>>(model_idx, W1a, W1b, W2a, W2b, ws);
  prep_final<<<dim3(kC), dim3(768), 0, stream>>>(model_idx, Wf, ws);
  prep_l0<<<dim3(kC), dim3(256), 0, stream>>>(model_idx, W0a, W0b, ws);
  wire_main<<<dim3(kC * (kN / kMB)), dim3(256), 0, stream>>>(
      inp, indices, model_idx, bias_idx, b0a, b0b,
      b1a, b1b, b2a, b2b, bff, ws, out);
}

// Round 21
// 190.033 us; speedup vs baseline: 1.4424x; 1.4424x over previous
//
#include <hip/hip_runtime.h>

typedef _Float16 f16;
typedef _Float16 f16x2 __attribute__((ext_vector_type(2)));
typedef _Float16 f16x8 __attribute__((ext_vector_type(8)));
typedef float f32x4 __attribute__((ext_vector_type(4)));

namespace {

constexpr int kC = 16, kN = 8192, kH = 181, kOut = 3;
constexpr int kMB = 64;            // points per block (4-tile B-hold)
constexpr int kKpad = 384;         // 12 ksteps * 32
constexpr int kNT = 48;            // tiles of 16 output-comps (4 neurons each)
constexpr int kKS = 12;            // k-steps of 32
constexpr int kRowB = 784;         // 768 data bytes + 16B pad (bank spread)
constexpr float kOmega = 30.f, kS2 = 100.f;

constexpr size_t kWLayerStride = (size_t)kNT * kKS * 64 * 8;  // f16 per (c,layer)
constexpr size_t kWfOff = kWLayerStride * kC * 2;             // f16 elems
constexpr size_t kWfStride = (size_t)kKS * 64 * 8;
constexpr size_t kW0Off = kWfOff + (size_t)kC * kWfStride;    // layer-0 frags
constexpr size_t kW0Stride = (size_t)kNT * 64 * 8;            // per c
constexpr size_t kBiasOff = kW0Off + (size_t)kC * kW0Stride;  // f16 units; packed
                                   // bias[c][L][q<192] f32x4 (re_a,im_a,re_b,im_b)

__device__ __forceinline__ int xadr(int row, int colb) { return row * kRowB + colb; }

// ---- prep: pack hidden-layer complex weights into fp16 fragment order
// ws[c][L][nt][ks][lane][8]; ALSO packs this (c,L,nt)'s 4 neurons' bias as
// f32x4[q] (zero-padded q>=181) so the main kernel loads bias with ONE
// dwordx4, branch-free, early (r19's float2x2+branch just-before-use was a
// ~250cyc exposed L2 latency 24x per wave per layer).
__global__ __launch_bounds__(768) void prep_hidden(
    const int* __restrict__ model_idx, const int* __restrict__ bias_idx,
    const float* __restrict__ W1a, const float* __restrict__ W1b,
    const float* __restrict__ W2a, const float* __restrict__ W2b,
    const float* __restrict__ b1a, const float* __restrict__ b1b,
    const float* __restrict__ b2a, const float* __restrict__ b2b,
    f16* __restrict__ ws)
{
  __shared__ float s[kH][2][4][2];   // [i][branch][o_sub][reim]
  const int bid = blockIdx.x;
  const int c  = bid / (2 * kNT);
  const int L  = (bid / kNT) % 2;
  const int nt = bid % kNT;
  const int m  = model_idx[c];
  const float* Wa = (L == 0 ? W1a : W2a) + (size_t)m * kH * kH * 2;
  const float* Wb = (L == 0 ? W1b : W2b) + (size_t)m * kH * kH * 2;
  const int t = threadIdx.x;
  if (t < 2 * kH) {
    const int i = t >> 1, br = t & 1;
    const float* src = (br ? Wb : Wa) + ((size_t)i * kH + nt * 4) * 2;
#pragma unroll
    for (int e = 0; e < 8; ++e) {
      const int osub = e >> 1, reim = e & 1;
      s[i][br][osub][reim] = (nt * 4 + osub < kH) ? src[osub * 2 + reim] : 0.f;
    }
  }
  // bias pack: t<16 covers (osub = t>>2, comp j = t&3)
  if (t < 16) {
    const int bix = bias_idx[c];
    const float* pa = (L == 0 ? b1a : b2a) + (size_t)bix * kH * 2;
    const float* pb = (L == 0 ? b1b : b2b) + (size_t)bix * kH * 2;
    const int osub = t >> 2, j = t & 3;
    const int q = nt * 4 + osub;
    float v = 0.f;
    if (q < kH) v = (j < 2) ? pa[q * 2 + j] : pb[q * 2 + (j - 2)];
    float* fb = (float*)(ws + kBiasOff);
    fb[((size_t)(c * 2 + L) * 192 + nt * 4) * 4 + t] = v;
  }
  __syncthreads();
  const int ks = t >> 6, lane = t & 63;
  const int kg = lane >> 4, l15 = lane & 15;
  const int osub = l15 >> 2, comp = l15 & 3, br = comp >> 1;
  const int o = nt * 4 + osub;
  f16x8 v;
#pragma unroll
  for (int j = 0; j < 8; ++j) {
    const int k = ks * 32 + kg * 8 + j;
    float f = 0.f;
    if (k < 2 * kH && o < kH) {
      const int i = k >> 1, kodd = k & 1;
      const int reim = kodd ? (1 - (comp & 1)) : (comp & 1);
      f = s[i][br][osub][reim];
      if (kodd && !(comp & 1)) f = -f;   // -w_im for real-output rows
    }
    v[j] = (f16)f;
  }
  *(f16x8*)&ws[(((size_t)(c * 2 + L) * kNT + nt) * kKS + ks) * 512 + lane * 8] = v;
}

// ---- prep: final layer (real part): col j<3, k=2i -> wf_re, 2i+1 -> -wf_im
__global__ __launch_bounds__(768) void prep_final(
    const int* __restrict__ model_idx, const float* __restrict__ Wf,
    f16* __restrict__ ws)
{
  const int c = blockIdx.x;
  const int m = model_idx[c];
  const int t = threadIdx.x;
  const int ks = t >> 6, lane = t & 63;
  const int kg = lane >> 4, col = lane & 15;
  f16x8 v;
#pragma unroll
  for (int j = 0; j < 8; ++j) {
    const int k = ks * 32 + kg * 8 + j;
    float f = 0.f;
    if (k < 2 * kH && col < kOut) {
      const int i = k >> 1;
      const float* p = &Wf[(((size_t)m * kH + i) * kOut + col) * 2];
      f = (k & 1) ? -p[1] : p[0];
    }
    v[j] = (f16)f;
  }
  *(f16x8*)&ws[kWfOff + ((size_t)c * kKS + ks) * 512 + lane * 8] = v;
}

// ---- prep: layer-0 A-frags. One K=32 tile, only k=0,1 valid.
// comp rows: (W0a[k][o], 0, W0b[k][o], 0) -> acc = (la, 0, lb, 0).
__global__ __launch_bounds__(256) void prep_l0(
    const int* __restrict__ model_idx,
    const float* __restrict__ W0a, const float* __restrict__ W0b,
    f16* __restrict__ ws)
{
  const int c = blockIdx.x;
  const int m = model_idx[c];
#pragma unroll 1
  for (int it = 0; it < 12; ++it) {
    const int slot = it * 256 + threadIdx.x;   // 48 nt x 64 lanes
    const int nt = slot >> 6, lane = slot & 63;
    const int kg = lane >> 4, l15 = lane & 15;
    const int osub = l15 >> 2, comp = l15 & 3;
    const int o = nt * 4 + osub;
    f16x8 v = {};
    if (kg == 0 && o < kH && (comp & 1) == 0) {
#pragma unroll
      for (int k = 0; k < 2; ++k) {
        const float f = (comp == 0) ? W0a[(m * 2 + k) * kH + o]
                                    : W0b[(m * 2 + k) * kH + o];
        v[k] = (f16)f;
      }
    }
    *(f16x8*)&ws[kW0Off + (size_t)c * kW0Stride + (size_t)slot * 8] = v;
  }
}

// ---- one hidden layer, IN PLACE, C^T, P=64, quarter-window A pipeline (r19)
// with packed-bias early load: ONE dwordx4 at mi-top (before the first
// sched_barrier -> issues ~1400cyc ahead of use; its waitcnt is subsumed by
// the A-load waits). No q<kH branch (prep zero-padded).
__device__ __forceinline__ void hidden_gemm(
    char* __restrict__ X, const f16x8* __restrict__ wl,
    const float* __restrict__ bp,   // packed bias[q] f32x4 for this (c,L)
    int w, int lane)
{
  const int kg = lane >> 4, l15 = lane & 15;
  f16x8 B[4][kKS];
#pragma unroll
  for (int pt = 0; pt < 4; ++pt)
#pragma unroll
    for (int ks = 0; ks < kKS; ++ks)
      B[pt][ks] = *(const f16x8*)(X + xadr(l15 + 16 * pt, ks * 64 + kg * 16));
  __syncthreads();   // all waves hold X in regs; X may now be overwritten

  f16x8 A0[3], A1[3];
  {  // prologue: first quarter of mi=0
    const f16x8* ap0 = wl + (size_t)(w * 12) * (kKS * 64) + lane;
#pragma unroll
    for (int j = 0; j < 3; ++j) A0[j] = ap0[j * 64];
  }

#pragma unroll 1
  for (int mi = 0; mi < 12; ++mi) {
    const int nt = w * 12 + mi;
    const int q = nt * 4 + kg;           // this lane's neuron
    const f16x8* ap = wl + (size_t)nt * (kKS * 64) + lane;
    // bias: one early branch-free load; lands during the 4 quarters
    const f32x4 bv = *(const f32x4*)(bp + (size_t)q * 4);
    f32x4 acc[4] = {};
    // Q0: issue ks3-5, consume A0 = ks0-2
#pragma unroll
    for (int j = 0; j < 3; ++j) A1[j] = ap[(3 + j) * 64];
    __builtin_amdgcn_sched_barrier(0);
    __builtin_amdgcn_s_setprio(1);
#pragma unroll
    for (int ks = 0; ks < 3; ++ks) {
      acc[0] = __builtin_amdgcn_mfma_f32_16x16x32_f16(A0[ks], B[0][ks], acc[0], 0, 0, 0);
      acc[1] = __builtin_amdgcn_mfma_f32_16x16x32_f16(A0[ks], B[1][ks], acc[1], 0, 0, 0);
      acc[2] = __builtin_amdgcn_mfma_f32_16x16x32_f16(A0[ks], B[2][ks], acc[2], 0, 0, 0);
      acc[3] = __builtin_amdgcn_mfma_f32_16x16x32_f16(A0[ks], B[3][ks], acc[3], 0, 0, 0);
    }
    __builtin_amdgcn_s_setprio(0);
    __builtin_amdgcn_sched_barrier(0);
    // Q1: issue ks6-8, consume A1 = ks3-5
#pragma unroll
    for (int j = 0; j < 3; ++j) A0[j] = ap[(6 + j) * 64];
    __builtin_amdgcn_sched_barrier(0);
    __builtin_amdgcn_s_setprio(1);
#pragma unroll
    for (int ks = 0; ks < 3; ++ks) {
      acc[0] = __builtin_amdgcn_mfma_f32_16x16x32_f16(A1[ks], B[0][3 + ks], acc[0], 0, 0, 0);
      acc[1] = __builtin_amdgcn_mfma_f32_16x16x32_f16(A1[ks], B[1][3 + ks], acc[1], 0, 0, 0);
      acc[2] = __builtin_amdgcn_mfma_f32_16x16x32_f16(A1[ks], B[2][3 + ks], acc[2], 0, 0, 0);
      acc[3] = __builtin_amdgcn_mfma_f32_16x16x32_f16(A1[ks], B[3][3 + ks], acc[3], 0, 0, 0);
    }
    __builtin_amdgcn_s_setprio(0);
    __builtin_amdgcn_sched_barrier(0);
    // Q2: issue ks9-11, consume A0 = ks6-8
#pragma unroll
    for (int j = 0; j < 3; ++j) A1[j] = ap[(9 + j) * 64];
    __builtin_amdgcn_sched_barrier(0);
    __builtin_amdgcn_s_setprio(1);
#pragma unroll
    for (int ks = 0; ks < 3; ++ks) {
      acc[0] = __builtin_amdgcn_mfma_f32_16x16x32_f16(A0[ks], B[0][6 + ks], acc[0], 0, 0, 0);
      acc[1] = __builtin_amdgcn_mfma_f32_16x16x32_f16(A0[ks], B[1][6 + ks], acc[1], 0, 0, 0);
      acc[2] = __builtin_amdgcn_mfma_f32_16x16x32_f16(A0[ks], B[2][6 + ks], acc[2], 0, 0, 0);
      acc[3] = __builtin_amdgcn_mfma_f32_16x16x32_f16(A0[ks], B[3][6 + ks], acc[3], 0, 0, 0);
    }
    __builtin_amdgcn_s_setprio(0);
    __builtin_amdgcn_sched_barrier(0);
    // Q3: issue next-mi ks0-2, consume A1 = ks9-11
#pragma unroll
    for (int j = 0; j < 3; ++j) A0[j] = ap[(kKS + j) * 64];
    __builtin_amdgcn_sched_barrier(0);
    __builtin_amdgcn_s_setprio(1);
#pragma unroll
    for (int ks = 0; ks < 3; ++ks) {
      acc[0] = __builtin_amdgcn_mfma_f32_16x16x32_f16(A1[ks], B[0][9 + ks], acc[0], 0, 0, 0);
      acc[1] = __builtin_amdgcn_mfma_f32_16x16x32_f16(A1[ks], B[1][9 + ks], acc[1], 0, 0, 0);
      acc[2] = __builtin_amdgcn_mfma_f32_16x16x32_f16(A1[ks], B[2][9 + ks], acc[2], 0, 0, 0);
      acc[3] = __builtin_amdgcn_mfma_f32_16x16x32_f16(A1[ks], B[3][9 + ks], acc[3], 0, 0, 0);
    }
    __builtin_amdgcn_s_setprio(0);
    // lane-local Gabor activation; overlaps the in-flight next-mi quarter.
#pragma unroll
    for (int pt = 0; pt < 4; ++pt) {
      const float v0 = acc[pt][0] + bv[0], v1 = acc[pt][1] + bv[1];
      const float v2 = acc[pt][2] + bv[2], v3 = acc[pt][3] + bv[3];
      const float mag = kS2 * (v0 * v0 + v1 * v1 + v2 * v2 + v3 * v3);
      const float amp = __expf(fmaf(-kOmega, v1, -mag));
      const float ph  = kOmega * v0;
      f16x2 pv = {(f16)(amp * __cosf(ph)), (f16)(amp * __sinf(ph))};
      *(f16x2*)(X + xadr(l15 + 16 * pt, q * 4)) = pv;
    }
  }
}

__global__ __launch_bounds__(256, 2)   // B 192 (AGPR) + windows 24 + acc 16
void wire_main(
    const float* __restrict__ inp, const int* __restrict__ indices,
    const int* __restrict__ model_idx, const int* __restrict__ bias_idx,
    const float* __restrict__ b0a, const float* __restrict__ b0b,
    const float* __restrict__ bf, const f16* __restrict__ wsW,
    float* __restrict__ out)
{
  __shared__ __align__(16) char X[kMB * kRowB];   // 49 KB single buffer
  const int d = blockIdx.x;
  const int lg = (d & 7) * 256 + (d >> 3);   // XCD swizzle (2048 % 8 == 0)
  const int c = lg >> 7;                     // 128 blocks per c
  const int n0 = (lg & 127) * kMB;
  const int src = indices[c], m = model_idx[c], bix = bias_idx[c];
  const int tid = threadIdx.x, w = tid >> 6, lane = tid & 63;
  const int kg = lane >> 4, l15 = lane & 15;

  // ---- layer 0 as MFMA (C^T): B = input coords (k=0,1 of one K-tile),
  // A = packed W0 frags; unified Gabor activation with v1=v3=0.
  {
    f16x8 Bx[4];
#pragma unroll
    for (int pt = 0; pt < 4; ++pt) {
      const int row = l15 + 16 * pt;
      const float2 xv = *(const float2*)&inp[((size_t)src * kN + n0 + row) * 2];
      f16x8 b = {};
      if (kg == 0) { b[0] = (f16)xv.x; b[1] = (f16)xv.y; }
      Bx[pt] = b;
    }
    const f16x8* w0p = (const f16x8*)(wsW + kW0Off + (size_t)c * kW0Stride);
    const float* b0av = b0a + (size_t)bix * kH;
    const float* b0bv = b0b + (size_t)bix * kH;
#pragma unroll 1
    for (int mi = 0; mi < 12; ++mi) {
      const int nt = w * 12 + mi;
      const int q = nt * 4 + kg;
      const f16x8 a = w0p[nt * 64 + lane];
      f32x4 acc[4] = {};
      __builtin_amdgcn_s_setprio(1);
      acc[0] = __builtin_amdgcn_mfma_f32_16x16x32_f16(a, Bx[0], acc[0], 0, 0, 0);
      acc[1] = __builtin_amdgcn_mfma_f32_16x16x32_f16(a, Bx[1], acc[1], 0, 0, 0);
      acc[2] = __builtin_amdgcn_mfma_f32_16x16x32_f16(a, Bx[2], acc[2], 0, 0, 0);
      acc[3] = __builtin_amdgcn_mfma_f32_16x16x32_f16(a, Bx[3], acc[3], 0, 0, 0);
      __builtin_amdgcn_s_setprio(0);
      float br_ = 0.f, cr_ = 0.f;
      if (q < kH) { br_ = b0av[q]; cr_ = b0bv[q]; }
#pragma unroll
      for (int pt = 0; pt < 4; ++pt) {
        const float v0 = acc[pt][0] + br_;
        const float v2 = acc[pt][2] + cr_;
        const float mag = kS2 * (v0 * v0 + v2 * v2);
        const float amp = __expf(-mag);
        const float ph  = kOmega * v0;
        f16x2 pv = {(f16)(amp * __cosf(ph)), (f16)(amp * __sinf(ph))};
        *(f16x2*)(&X[0] + xadr(l15 + 16 * pt, q * 4)) = pv;
      }
    }
  }
  __syncthreads();
  const float* biasB = (const float*)(wsW + kBiasOff);
  hidden_gemm(X, (const f16x8*)(wsW + (size_t)(c * 2 + 0) * kWLayerStride),
              biasB + (size_t)(c * 2 + 0) * 192 * 4, w, lane);
  __syncthreads();
  hidden_gemm(X, (const f16x8*)(wsW + (size_t)(c * 2 + 1) * kWLayerStride),
              biasB + (size_t)(c * 2 + 1) * 192 * 4, w, lane);
  __syncthreads();
  // ---- final complex 181->3, real part; wave w owns point-tile w
  {
    const f16x8* wf = (const f16x8*)(wsW + kWfOff + (size_t)c * kWfStride);
    f32x4 facc = {0.f, 0.f, 0.f, 0.f};
#pragma unroll
    for (int ks = 0; ks < kKS; ++ks) {
      f16x8 a = *(const f16x8*)(&X[0] + xadr(l15 + 16 * w, ks * 64 + kg * 16));
      f16x8 b = wf[(size_t)ks * 64 + lane];
      facc = __builtin_amdgcn_mfma_f32_16x16x32_f16(a, b, facc, 0, 0, 0);
    }
    if (l15 < kOut) {
      const float bfr = bf[(bix * kOut + l15) * 2];
#pragma unroll
      for (int j = 0; j < 4; ++j) {
        const int row = w * 16 + kg * 4 + j;
        out[((size_t)c * kN + n0 + row) * kOut + l15] = facc[j] + bfr;
      }
    }
  }
}

}  // namespace

extern "C" void kernel_launch(void* const* d_in, const int* in_sizes, int n_in,
                              void* d_out, int out_size, void* d_ws, size_t ws_size,
                              hipStream_t stream) {
  const float* inp       = (const float*)d_in[0];
  const int*   indices   = (const int*)  d_in[1];
  const int*   model_idx = (const int*)  d_in[2];
  const int*   bias_idx  = (const int*)  d_in[3];
  const float* W0a = (const float*)d_in[4];
  const float* b0a = (const float*)d_in[5];
  const float* W0b = (const float*)d_in[6];
  const float* b0b = (const float*)d_in[7];
  const float* W1a = (const float*)d_in[8];
  const float* b1a = (const float*)d_in[9];
  const float* W1b = (const float*)d_in[10];
  const float* b1b = (const float*)d_in[11];
  const float* W2a = (const float*)d_in[12];
  const float* b2a = (const float*)d_in[13];
  const float* W2b = (const float*)d_in[14];
  const float* b2b = (const float*)d_in[15];
  const float* Wf  = (const float*)d_in[16];
  const float* bff = (const float*)d_in[17];
  f16*   ws  = (f16*)d_ws;     // needs ~20.0 MB
  float* out = (float*)d_out;

  prep_hidden<<<dim3(kC * 2 * kNT), dim3(768), 0, stream>>>(
      model_idx, bias_idx, W1a, W1b, W2a, W2b, b1a, b1b, b2a, b2b, ws);
  prep_final<<<dim3(kC), dim3(768), 0, stream>>>(model_idx, Wf, ws);
  prep_l0<<<dim3(kC), dim3(256), 0, stream>>>(model_idx, W0a, W0b, ws);
  wire_main<<<dim3(kC * (kN / kMB)), dim3(256), 0, stream>>>(
      inp, indices, model_idx, bias_idx, b0a, b0b,
      bff, ws, out);
}

// Round 22
// 187.658 us; speedup vs baseline: 1.4606x; 1.0127x over previous
//
#include <hip/hip_runtime.h>

typedef _Float16 f16;
typedef _Float16 f16x2 __attribute__((ext_vector_type(2)));
typedef _Float16 f16x8 __attribute__((ext_vector_type(8)));
typedef float f32x4 __attribute__((ext_vector_type(4)));

namespace {

constexpr int kC = 16, kN = 8192, kH = 181, kOut = 3;
constexpr int kMB = 64;            // points per block (4-tile B-hold)
constexpr int kKpad = 384;         // 12 ksteps * 32
constexpr int kNT = 48;            // tiles of 16 output-comps (4 neurons each)
constexpr int kKS = 12;            // k-steps of 32
constexpr int kRowB = 784;         // 768 data bytes + 16B pad (bank spread)
constexpr float kOmega = 30.f, kS2 = 100.f;

constexpr size_t kWLayerStride = (size_t)kNT * kKS * 64 * 8;  // f16 per (c,layer)
constexpr size_t kWfOff = kWLayerStride * kC * 2;             // f16 elems
constexpr size_t kWfStride = (size_t)kKS * 64 * 8;
constexpr size_t kW0Off = kWfOff + (size_t)kC * kWfStride;    // layer-0 frags
constexpr size_t kW0Stride = (size_t)kNT * 64 * 8;            // per c
constexpr size_t kBiasOff = kW0Off + (size_t)kC * kW0Stride;  // f16 units; packed
                                   // bias[c][L][q<192] f32x4 (re_a,im_a,re_b,im_b)

__device__ __forceinline__ int xadr(int row, int colb) { return row * kRowB + colb; }

// ---- prep: pack hidden-layer complex weights into fp16 fragment order
// ws[c][L][nt][ks][lane][8]; ALSO packs this (c,L,nt)'s 4 neurons' bias as
// f32x4[q] (zero-padded q>=181) so the main kernel loads bias with ONE
// dwordx4, branch-free, early.
__global__ __launch_bounds__(768) void prep_hidden(
    const int* __restrict__ model_idx, const int* __restrict__ bias_idx,
    const float* __restrict__ W1a, const float* __restrict__ W1b,
    const float* __restrict__ W2a, const float* __restrict__ W2b,
    const float* __restrict__ b1a, const float* __restrict__ b1b,
    const float* __restrict__ b2a, const float* __restrict__ b2b,
    f16* __restrict__ ws)
{
  __shared__ float s[kH][2][4][2];   // [i][branch][o_sub][reim]
  const int bid = blockIdx.x;
  const int c  = bid / (2 * kNT);
  const int L  = (bid / kNT) % 2;
  const int nt = bid % kNT;
  const int m  = model_idx[c];
  const float* Wa = (L == 0 ? W1a : W2a) + (size_t)m * kH * kH * 2;
  const float* Wb = (L == 0 ? W1b : W2b) + (size_t)m * kH * kH * 2;
  const int t = threadIdx.x;
  if (t < 2 * kH) {
    const int i = t >> 1, br = t & 1;
    const float* src = (br ? Wb : Wa) + ((size_t)i * kH + nt * 4) * 2;
#pragma unroll
    for (int e = 0; e < 8; ++e) {
      const int osub = e >> 1, reim = e & 1;
      s[i][br][osub][reim] = (nt * 4 + osub < kH) ? src[osub * 2 + reim] : 0.f;
    }
  }
  // bias pack: t<16 covers (osub = t>>2, comp j = t&3)
  if (t < 16) {
    const int bix = bias_idx[c];
    const float* pa = (L == 0 ? b1a : b2a) + (size_t)bix * kH * 2;
    const float* pb = (L == 0 ? b1b : b2b) + (size_t)bix * kH * 2;
    const int osub = t >> 2, j = t & 3;
    const int q = nt * 4 + osub;
    float v = 0.f;
    if (q < kH) v = (j < 2) ? pa[q * 2 + j] : pb[q * 2 + (j - 2)];
    float* fb = (float*)(ws + kBiasOff);
    fb[((size_t)(c * 2 + L) * 192 + nt * 4) * 4 + t] = v;
  }
  __syncthreads();
  const int ks = t >> 6, lane = t & 63;
  const int kg = lane >> 4, l15 = lane & 15;
  const int osub = l15 >> 2, comp = l15 & 3, br = comp >> 1;
  const int o = nt * 4 + osub;
  f16x8 v;
#pragma unroll
  for (int j = 0; j < 8; ++j) {
    const int k = ks * 32 + kg * 8 + j;
    float f = 0.f;
    if (k < 2 * kH && o < kH) {
      const int i = k >> 1, kodd = k & 1;
      const int reim = kodd ? (1 - (comp & 1)) : (comp & 1);
      f = s[i][br][osub][reim];
      if (kodd && !(comp & 1)) f = -f;   // -w_im for real-output rows
    }
    v[j] = (f16)f;
  }
  *(f16x8*)&ws[(((size_t)(c * 2 + L) * kNT + nt) * kKS + ks) * 512 + lane * 8] = v;
}

// ---- prep: final layer (real part): col j<3, k=2i -> wf_re, 2i+1 -> -wf_im
__global__ __launch_bounds__(768) void prep_final(
    const int* __restrict__ model_idx, const float* __restrict__ Wf,
    f16* __restrict__ ws)
{
  const int c = blockIdx.x;
  const int m = model_idx[c];
  const int t = threadIdx.x;
  const int ks = t >> 6, lane = t & 63;
  const int kg = lane >> 4, col = lane & 15;
  f16x8 v;
#pragma unroll
  for (int j = 0; j < 8; ++j) {
    const int k = ks * 32 + kg * 8 + j;
    float f = 0.f;
    if (k < 2 * kH && col < kOut) {
      const int i = k >> 1;
      const float* p = &Wf[(((size_t)m * kH + i) * kOut + col) * 2];
      f = (k & 1) ? -p[1] : p[0];
    }
    v[j] = (f16)f;
  }
  *(f16x8*)&ws[kWfOff + ((size_t)c * kKS + ks) * 512 + lane * 8] = v;
}

// ---- prep: layer-0 A-frags. One K=32 tile, only k=0,1 valid.
// comp rows: (W0a[k][o], 0, W0b[k][o], 0) -> acc = (la, 0, lb, 0).
__global__ __launch_bounds__(256) void prep_l0(
    const int* __restrict__ model_idx,
    const float* __restrict__ W0a, const float* __restrict__ W0b,
    f16* __restrict__ ws)
{
  const int c = blockIdx.x;
  const int m = model_idx[c];
#pragma unroll 1
  for (int it = 0; it < 12; ++it) {
    const int slot = it * 256 + threadIdx.x;   // 48 nt x 64 lanes
    const int nt = slot >> 6, lane = slot & 63;
    const int kg = lane >> 4, l15 = lane & 15;
    const int osub = l15 >> 2, comp = l15 & 3;
    const int o = nt * 4 + osub;
    f16x8 v = {};
    if (kg == 0 && o < kH && (comp & 1) == 0) {
#pragma unroll
      for (int k = 0; k < 2; ++k) {
        const float f = (comp == 0) ? W0a[(m * 2 + k) * kH + o]
                                    : W0b[(m * 2 + k) * kH + o];
        v[k] = (f16)f;
      }
    }
    *(f16x8*)&ws[kW0Off + (size_t)c * kW0Stride + (size_t)slot * 8] = v;
  }
}

// issue 2 A-frags into a named window; consume 2 ks of a window (8 MFMAs).
#define ISSUE2(WIN, J0) { WIN[0] = ap[(J0) * 64]; WIN[1] = ap[(J0 + 1) * 64]; }
#define SLOT2(WIN, KSB)                                                        \
  __builtin_amdgcn_sched_barrier(0);                                           \
  __builtin_amdgcn_s_setprio(1);                                               \
  _Pragma("unroll")                                                            \
  for (int k2 = 0; k2 < 2; ++k2) {                                             \
    acc[0] = __builtin_amdgcn_mfma_f32_16x16x32_f16(WIN[k2], B[0][(KSB) + k2], acc[0], 0, 0, 0); \
    acc[1] = __builtin_amdgcn_mfma_f32_16x16x32_f16(WIN[k2], B[1][(KSB) + k2], acc[1], 0, 0, 0); \
    acc[2] = __builtin_amdgcn_mfma_f32_16x16x32_f16(WIN[k2], B[2][(KSB) + k2], acc[2], 0, 0, 0); \
    acc[3] = __builtin_amdgcn_mfma_f32_16x16x32_f16(WIN[k2], B[3][(KSB) + k2], acc[3], 0, 0, 0); \
  }                                                                            \
  __builtin_amdgcn_s_setprio(0);                                               \
  __builtin_amdgcn_sched_barrier(0);

// ---- one hidden layer, IN PLACE, C^T, P=64, THREE-WINDOW PAIR ROTATION.
// Same 24 window-VGPRs as r19/r21 (proven spill-free beside the 192-AGPR
// B-hold), but rotated as 3 windows x 2 frags over six 2-ks slots: slot g
// issues window (g+2)%3 and consumes window g%3 -> issue-to-consume distance
// = 2 slots (~350 cyc) instead of 1 quarter (~260) — deeper shadow for the
// L2 latency that r21's counters show as the remaining ~50% stall.
// Slots 4/5 prefetch next mi's ks0-3 (mi=11 lookahead lands in adjacent ws).
__device__ __forceinline__ void hidden_gemm(
    char* __restrict__ X, const f16x8* __restrict__ wl,
    const float* __restrict__ bp,   // packed bias[q] f32x4 for this (c,L)
    int w, int lane)
{
  const int kg = lane >> 4, l15 = lane & 15;
  f16x8 B[4][kKS];
#pragma unroll
  for (int pt = 0; pt < 4; ++pt)
#pragma unroll
    for (int ks = 0; ks < kKS; ++ks)
      B[pt][ks] = *(const f16x8*)(X + xadr(l15 + 16 * pt, ks * 64 + kg * 16));
  __syncthreads();   // all waves hold X in regs; X may now be overwritten

  f16x8 A0[2], A1[2], A2[2];
  {  // prologue: windows 0,1 of mi=0 (ks0-3)
    const f16x8* ap = wl + (size_t)(w * 12) * (kKS * 64) + lane;
    ISSUE2(A0, 0)
    ISSUE2(A1, 2)
  }

#pragma unroll 1
  for (int mi = 0; mi < 12; ++mi) {
    const int nt = w * 12 + mi;
    const int q = nt * 4 + kg;           // this lane's neuron
    const f16x8* ap = wl + (size_t)nt * (kKS * 64) + lane;
    // bias: one early branch-free load; lands during the 6 slots
    const f32x4 bv = *(const f32x4*)(bp + (size_t)q * 4);
    f32x4 acc[4] = {};
    ISSUE2(A2, 4)   SLOT2(A0, 0)    // consume ks0,1 (issued 2 slots ago)
    ISSUE2(A0, 6)   SLOT2(A1, 2)
    ISSUE2(A1, 8)   SLOT2(A2, 4)
    ISSUE2(A2, 10)  SLOT2(A0, 6)
    ISSUE2(A0, 12)  SLOT2(A1, 8)    // issues next-mi ks0,1
    ISSUE2(A1, 14)  SLOT2(A2, 10)   // issues next-mi ks2,3
    // lane-local Gabor activation; overlaps the in-flight next-mi windows.
#pragma unroll
    for (int pt = 0; pt < 4; ++pt) {
      const float v0 = acc[pt][0] + bv[0], v1 = acc[pt][1] + bv[1];
      const float v2 = acc[pt][2] + bv[2], v3 = acc[pt][3] + bv[3];
      const float mag = kS2 * (v0 * v0 + v1 * v1 + v2 * v2 + v3 * v3);
      const float amp = __expf(fmaf(-kOmega, v1, -mag));
      const float ph  = kOmega * v0;
      f16x2 pv = {(f16)(amp * __cosf(ph)), (f16)(amp * __sinf(ph))};
      *(f16x2*)(X + xadr(l15 + 16 * pt, q * 4)) = pv;
    }
  }
}

__global__ __launch_bounds__(256, 2)   // B 192 (AGPR) + windows 24 + acc 16
void wire_main(
    const float* __restrict__ inp, const int* __restrict__ indices,
    const int* __restrict__ model_idx, const int* __restrict__ bias_idx,
    const float* __restrict__ b0a, const float* __restrict__ b0b,
    const float* __restrict__ bf, const f16* __restrict__ wsW,
    float* __restrict__ out)
{
  __shared__ __align__(16) char X[kMB * kRowB];   // 49 KB single buffer
  const int d = blockIdx.x;
  const int lg = (d & 7) * 256 + (d >> 3);   // XCD swizzle (2048 % 8 == 0)
  const int c = lg >> 7;                     // 128 blocks per c
  const int n0 = (lg & 127) * kMB;
  const int src = indices[c], m = model_idx[c], bix = bias_idx[c];
  const int tid = threadIdx.x, w = tid >> 6, lane = tid & 63;
  const int kg = lane >> 4, l15 = lane & 15;

  // ---- layer 0 as MFMA (C^T): B = input coords (k=0,1 of one K-tile),
  // A = packed W0 frags; unified Gabor activation with v1=v3=0.
  {
    f16x8 Bx[4];
#pragma unroll
    for (int pt = 0; pt < 4; ++pt) {
      const int row = l15 + 16 * pt;
      const float2 xv = *(const float2*)&inp[((size_t)src * kN + n0 + row) * 2];
      f16x8 b = {};
      if (kg == 0) { b[0] = (f16)xv.x; b[1] = (f16)xv.y; }
      Bx[pt] = b;
    }
    const f16x8* w0p = (const f16x8*)(wsW + kW0Off + (size_t)c * kW0Stride);
    const float* b0av = b0a + (size_t)bix * kH;
    const float* b0bv = b0b + (size_t)bix * kH;
#pragma unroll 1
    for (int mi = 0; mi < 12; ++mi) {
      const int nt = w * 12 + mi;
      const int q = nt * 4 + kg;
      const f16x8 a = w0p[nt * 64 + lane];
      f32x4 acc[4] = {};
      __builtin_amdgcn_s_setprio(1);
      acc[0] = __builtin_amdgcn_mfma_f32_16x16x32_f16(a, Bx[0], acc[0], 0, 0, 0);
      acc[1] = __builtin_amdgcn_mfma_f32_16x16x32_f16(a, Bx[1], acc[1], 0, 0, 0);
      acc[2] = __builtin_amdgcn_mfma_f32_16x16x32_f16(a, Bx[2], acc[2], 0, 0, 0);
      acc[3] = __builtin_amdgcn_mfma_f32_16x16x32_f16(a, Bx[3], acc[3], 0, 0, 0);
      __builtin_amdgcn_s_setprio(0);
      float br_ = 0.f, cr_ = 0.f;
      if (q < kH) { br_ = b0av[q]; cr_ = b0bv[q]; }
#pragma unroll
      for (int pt = 0; pt < 4; ++pt) {
        const float v0 = acc[pt][0] + br_;
        const float v2 = acc[pt][2] + cr_;
        const float mag = kS2 * (v0 * v0 + v2 * v2);
        const float amp = __expf(-mag);
        const float ph  = kOmega * v0;
        f16x2 pv = {(f16)(amp * __cosf(ph)), (f16)(amp * __sinf(ph))};
        *(f16x2*)(&X[0] + xadr(l15 + 16 * pt, q * 4)) = pv;
      }
    }
  }
  __syncthreads();
  const float* biasB = (const float*)(wsW + kBiasOff);
  hidden_gemm(X, (const f16x8*)(wsW + (size_t)(c * 2 + 0) * kWLayerStride),
              biasB + (size_t)(c * 2 + 0) * 192 * 4, w, lane);
  __syncthreads();
  hidden_gemm(X, (const f16x8*)(wsW + (size_t)(c * 2 + 1) * kWLayerStride),
              biasB + (size_t)(c * 2 + 1) * 192 * 4, w, lane);
  __syncthreads();
  // ---- final complex 181->3, real part; wave w owns point-tile w
  {
    const f16x8* wf = (const f16x8*)(wsW + kWfOff + (size_t)c * kWfStride);
    f32x4 facc = {0.f, 0.f, 0.f, 0.f};
#pragma unroll
    for (int ks = 0; ks < kKS; ++ks) {
      f16x8 a = *(const f16x8*)(&X[0] + xadr(l15 + 16 * w, ks * 64 + kg * 16));
      f16x8 b = wf[(size_t)ks * 64 + lane];
      facc = __builtin_amdgcn_mfma_f32_16x16x32_f16(a, b, facc, 0, 0, 0);
    }
    if (l15 < kOut) {
      const float bfr = bf[(bix * kOut + l15) * 2];
#pragma unroll
      for (int j = 0; j < 4; ++j) {
        const int row = w * 16 + kg * 4 + j;
        out[((size_t)c * kN + n0 + row) * kOut + l15] = facc[j] + bfr;
      }
    }
  }
}

}  // namespace

extern "C" void kernel_launch(void* const* d_in, const int* in_sizes, int n_in,
                              void* d_out, int out_size, void* d_ws, size_t ws_size,
                              hipStream_t stream) {
  const float* inp       = (const float*)d_in[0];
  const int*   indices   = (const int*)  d_in[1];
  const int*   model_idx = (const int*)  d_in[2];
  const int*   bias_idx  = (const int*)  d_in[3];
  const float* W0a = (const float*)d_in[4];
  const float* b0a = (const float*)d_in[5];
  const float* W0b = (const float*)d_in[6];
  const float* b0b = (const float*)d_in[7];
  const float* W1a = (const float*)d_in[8];
  const float* b1a = (const float*)d_in[9];
  const float* W1b = (const float*)d_in[10];
  const float* b1b = (const float*)d_in[11];
  const float* W2a = (const float*)d_in[12];
  const float* b2a = (const float*)d_in[13];
  const float* W2b = (const float*)d_in[14];
  const float* b2b = (const float*)d_in[15];
  const float* Wf  = (const float*)d_in[16];
  const float* bff = (const float*)d_in[17];
  f16*   ws  = (f16*)d_ws;     // needs ~20.0 MB
  float* out = (float*)d_out;

  prep_hidden<<<dim3(kC * 2 * kNT), dim3(768), 0, stream>>>(
      model_idx, bias_idx, W1a, W1b, W2a, W2b, b1a, b1b, b2a, b2b, ws);
  prep_final<<<dim3(kC), dim3(768), 0, stream>>>(model_idx, Wf, ws);
  prep_l0<<<dim3(kC), dim3(256), 0, stream>>>(model_idx, W0a, W0b, ws);
  wire_main<<<dim3(kC * (kN / kMB)), dim3(256), 0, stream>>>(
      inp, indices, model_idx, bias_idx, b0a, b0b,
      bff, ws, out);
}

// Round 23
// 182.284 us; speedup vs baseline: 1.5037x; 1.0295x over previous
//
#include <hip/hip_runtime.h>

typedef _Float16 f16;
typedef _Float16 f16x2 __attribute__((ext_vector_type(2)));
typedef _Float16 f16x8 __attribute__((ext_vector_type(8)));
typedef float f32x4 __attribute__((ext_vector_type(4)));

namespace {

constexpr int kC = 16, kN = 8192, kH = 181, kOut = 3;
constexpr int kMB = 64;            // points per block (4-tile B-hold)
constexpr int kKpad = 384;         // 12 ksteps * 32
constexpr int kNT = 48;            // tiles of 16 output-comps (4 neurons each)
constexpr int kKS = 12;            // k-steps of 32
constexpr int kRowB = 784;         // 768 data bytes + 16B pad (bank spread)
constexpr float kOmega = 30.f, kS2 = 100.f;

constexpr size_t kWLayerStride = (size_t)kNT * kKS * 64 * 8;  // f16 per (c,layer)
constexpr size_t kWfOff = kWLayerStride * kC * 2;             // f16 elems
constexpr size_t kWfStride = (size_t)kKS * 64 * 8;
constexpr size_t kW0Off = kWfOff + (size_t)kC * kWfStride;    // layer-0 frags
constexpr size_t kW0Stride = (size_t)kNT * 64 * 8;            // per c
constexpr size_t kBiasOff = kW0Off + (size_t)kC * kW0Stride;  // f16 units; packed
                                   // bias[c][L][q<192] f32x4 (re_a,im_a,re_b,im_b)

__device__ __forceinline__ int xadr(int row, int colb) { return row * kRowB + colb; }

// ---- prep: pack hidden-layer complex weights into fp16 fragment order
// ws[c][L][nt][ks][lane][8]; ALSO packs this (c,L,nt)'s 4 neurons' bias as
// f32x4[q] (zero-padded q>=181) so the main kernel loads bias with ONE
// dwordx4, branch-free, early.
__global__ __launch_bounds__(768) void prep_hidden(
    const int* __restrict__ model_idx, const int* __restrict__ bias_idx,
    const float* __restrict__ W1a, const float* __restrict__ W1b,
    const float* __restrict__ W2a, const float* __restrict__ W2b,
    const float* __restrict__ b1a, const float* __restrict__ b1b,
    const float* __restrict__ b2a, const float* __restrict__ b2b,
    f16* __restrict__ ws)
{
  __shared__ float s[kH][2][4][2];   // [i][branch][o_sub][reim]
  const int bid = blockIdx.x;
  const int c  = bid / (2 * kNT);
  const int L  = (bid / kNT) % 2;
  const int nt = bid % kNT;
  const int m  = model_idx[c];
  const float* Wa = (L == 0 ? W1a : W2a) + (size_t)m * kH * kH * 2;
  const float* Wb = (L == 0 ? W1b : W2b) + (size_t)m * kH * kH * 2;
  const int t = threadIdx.x;
  if (t < 2 * kH) {
    const int i = t >> 1, br = t & 1;
    const float* src = (br ? Wb : Wa) + ((size_t)i * kH + nt * 4) * 2;
#pragma unroll
    for (int e = 0; e < 8; ++e) {
      const int osub = e >> 1, reim = e & 1;
      s[i][br][osub][reim] = (nt * 4 + osub < kH) ? src[osub * 2 + reim] : 0.f;
    }
  }
  // bias pack: t<16 covers (osub = t>>2, comp j = t&3)
  if (t < 16) {
    const int bix = bias_idx[c];
    const float* pa = (L == 0 ? b1a : b2a) + (size_t)bix * kH * 2;
    const float* pb = (L == 0 ? b1b : b2b) + (size_t)bix * kH * 2;
    const int osub = t >> 2, j = t & 3;
    const int q = nt * 4 + osub;
    float v = 0.f;
    if (q < kH) v = (j < 2) ? pa[q * 2 + j] : pb[q * 2 + (j - 2)];
    float* fb = (float*)(ws + kBiasOff);
    fb[((size_t)(c * 2 + L) * 192 + nt * 4) * 4 + t] = v;
  }
  __syncthreads();
  const int ks = t >> 6, lane = t & 63;
  const int kg = lane >> 4, l15 = lane & 15;
  const int osub = l15 >> 2, comp = l15 & 3, br = comp >> 1;
  const int o = nt * 4 + osub;
  f16x8 v;
#pragma unroll
  for (int j = 0; j < 8; ++j) {
    const int k = ks * 32 + kg * 8 + j;
    float f = 0.f;
    if (k < 2 * kH && o < kH) {
      const int i = k >> 1, kodd = k & 1;
      const int reim = kodd ? (1 - (comp & 1)) : (comp & 1);
      f = s[i][br][osub][reim];
      if (kodd && !(comp & 1)) f = -f;   // -w_im for real-output rows
    }
    v[j] = (f16)f;
  }
  *(f16x8*)&ws[(((size_t)(c * 2 + L) * kNT + nt) * kKS + ks) * 512 + lane * 8] = v;
}

// ---- prep: final layer (real part): col j<3, k=2i -> wf_re, 2i+1 -> -wf_im
__global__ __launch_bounds__(768) void prep_final(
    const int* __restrict__ model_idx, const float* __restrict__ Wf,
    f16* __restrict__ ws)
{
  const int c = blockIdx.x;
  const int m = model_idx[c];
  const int t = threadIdx.x;
  const int ks = t >> 6, lane = t & 63;
  const int kg = lane >> 4, col = lane & 15;
  f16x8 v;
#pragma unroll
  for (int j = 0; j < 8; ++j) {
    const int k = ks * 32 + kg * 8 + j;
    float f = 0.f;
    if (k < 2 * kH && col < kOut) {
      const int i = k >> 1;
      const float* p = &Wf[(((size_t)m * kH + i) * kOut + col) * 2];
      f = (k & 1) ? -p[1] : p[0];
    }
    v[j] = (f16)f;
  }
  *(f16x8*)&ws[kWfOff + ((size_t)c * kKS + ks) * 512 + lane * 8] = v;
}

// ---- prep: layer-0 A-frags. One K=32 tile, only k=0,1 valid.
// comp rows: (W0a[k][o], 0, W0b[k][o], 0) -> acc = (la, 0, lb, 0).
__global__ __launch_bounds__(256) void prep_l0(
    const int* __restrict__ model_idx,
    const float* __restrict__ W0a, const float* __restrict__ W0b,
    f16* __restrict__ ws)
{
  const int c = blockIdx.x;
  const int m = model_idx[c];
#pragma unroll 1
  for (int it = 0; it < 12; ++it) {
    const int slot = it * 256 + threadIdx.x;   // 48 nt x 64 lanes
    const int nt = slot >> 6, lane = slot & 63;
    const int kg = lane >> 4, l15 = lane & 15;
    const int osub = l15 >> 2, comp = l15 & 3;
    const int o = nt * 4 + osub;
    f16x8 v = {};
    if (kg == 0 && o < kH && (comp & 1) == 0) {
#pragma unroll
      for (int k = 0; k < 2; ++k) {
        const float f = (comp == 0) ? W0a[(m * 2 + k) * kH + o]
                                    : W0b[(m * 2 + k) * kH + o];
        v[k] = (f16)f;
      }
    }
    *(f16x8*)&ws[kW0Off + (size_t)c * kW0Stride + (size_t)slot * 8] = v;
  }
}

// issue 2 A-frags into a named window; consume 2 ks of a window (8 MFMAs).
#define ISSUE2(WIN, J0) { WIN[0] = ap[(J0) * 64]; WIN[1] = ap[(J0 + 1) * 64]; }
#define SLOT2(WIN, KSB)                                                        \
  __builtin_amdgcn_sched_barrier(0);                                           \
  __builtin_amdgcn_s_setprio(1);                                               \
  _Pragma("unroll")                                                            \
  for (int k2 = 0; k2 < 2; ++k2) {                                             \
    acc[0] = __builtin_amdgcn_mfma_f32_16x16x32_f16(WIN[k2], B[0][(KSB) + k2], acc[0], 0, 0, 0); \
    acc[1] = __builtin_amdgcn_mfma_f32_16x16x32_f16(WIN[k2], B[1][(KSB) + k2], acc[1], 0, 0, 0); \
    acc[2] = __builtin_amdgcn_mfma_f32_16x16x32_f16(WIN[k2], B[2][(KSB) + k2], acc[2], 0, 0, 0); \
    acc[3] = __builtin_amdgcn_mfma_f32_16x16x32_f16(WIN[k2], B[3][(KSB) + k2], acc[3], 0, 0, 0); \
  }                                                                            \
  __builtin_amdgcn_s_setprio(0);                                               \
  __builtin_amdgcn_sched_barrier(0);

// ---- one hidden layer, IN PLACE, C^T, P=64, three-window pair rotation
// (r22, neutral-vs-r21 but kept: issue distance 2 slots). B-hold 192 AGPR.
__device__ __forceinline__ void hidden_gemm(
    char* __restrict__ X, const f16x8* __restrict__ wl,
    const float* __restrict__ bp,   // packed bias[q] f32x4 for this (c,L)
    int w, int lane)
{
  const int kg = lane >> 4, l15 = lane & 15;
  f16x8 B[4][kKS];
#pragma unroll
  for (int pt = 0; pt < 4; ++pt)
#pragma unroll
    for (int ks = 0; ks < kKS; ++ks)
      B[pt][ks] = *(const f16x8*)(X + xadr(l15 + 16 * pt, ks * 64 + kg * 16));
  __syncthreads();   // all waves hold X in regs; X may now be overwritten

  f16x8 A0[2], A1[2], A2[2];
  {  // prologue: windows 0,1 of mi=0 (ks0-3)
    const f16x8* ap = wl + (size_t)(w * 12) * (kKS * 64) + lane;
    ISSUE2(A0, 0)
    ISSUE2(A1, 2)
  }

#pragma unroll 1
  for (int mi = 0; mi < 12; ++mi) {
    const int nt = w * 12 + mi;
    const int q = nt * 4 + kg;           // this lane's neuron
    const f16x8* ap = wl + (size_t)nt * (kKS * 64) + lane;
    // bias: one early branch-free load; lands during the 6 slots
    const f32x4 bv = *(const f32x4*)(bp + (size_t)q * 4);
    f32x4 acc[4] = {};
    ISSUE2(A2, 4)   SLOT2(A0, 0)    // consume ks0,1 (issued 2 slots ago)
    ISSUE2(A0, 6)   SLOT2(A1, 2)
    ISSUE2(A1, 8)   SLOT2(A2, 4)
    ISSUE2(A2, 10)  SLOT2(A0, 6)
    ISSUE2(A0, 12)  SLOT2(A1, 8)    // issues next-mi ks0,1
    ISSUE2(A1, 14)  SLOT2(A2, 10)   // issues next-mi ks2,3
    // lane-local Gabor activation; overlaps the in-flight next-mi windows.
#pragma unroll
    for (int pt = 0; pt < 4; ++pt) {
      const float v0 = acc[pt][0] + bv[0], v1 = acc[pt][1] + bv[1];
      const float v2 = acc[pt][2] + bv[2], v3 = acc[pt][3] + bv[3];
      const float mag = kS2 * (v0 * v0 + v1 * v1 + v2 * v2 + v3 * v3);
      const float amp = __expf(fmaf(-kOmega, v1, -mag));
      const float ph  = kOmega * v0;
      f16x2 pv = {(f16)(amp * __cosf(ph)), (f16)(amp * __sinf(ph))};
      *(f16x2*)(X + xadr(l15 + 16 * pt, q * 4)) = pv;
    }
  }
}

__global__ __launch_bounds__(256, 2)   // B 192 (AGPR) + windows 24 + acc 16
void wire_main(
    const float* __restrict__ inp, const int* __restrict__ indices,
    const int* __restrict__ model_idx, const int* __restrict__ bias_idx,
    const float* __restrict__ b0a, const float* __restrict__ b0b,
    const float* __restrict__ bf, const f16* __restrict__ wsW,
    float* __restrict__ out)
{
  __shared__ __align__(16) char X[kMB * kRowB];   // 49 KB single buffer
  const int d = blockIdx.x;
  const int lg = (d & 7) * 256 + (d >> 3);   // XCD swizzle (2048 % 8 == 0)
  const int c = lg >> 7;                     // 128 blocks per c
  const int n0 = (lg & 127) * kMB;
  const int src = indices[c], m = model_idx[c], bix = bias_idx[c];
  const int tid = threadIdx.x, w = tid >> 6, lane = tid & 63;
  const int kg = lane >> 4, l15 = lane & 15;

  // ---- layer 0 as MFMA (C^T), SOFTWARE-PIPELINED one iteration deep:
  // 2 mi per loop iteration; mi+2/mi+3's A-frag+bias issued at the top ->
  // issue-to-consume distance ~ one body (>=700cyc) instead of 0 (r22's L0
  // loaded each frag immediately before use: ~450cyc exposed x12 per wave).
  // L0 has no B-hold live -> registers are free here.
  {
    f16x8 Bx[4];
#pragma unroll
    for (int pt = 0; pt < 4; ++pt) {
      const int row = l15 + 16 * pt;
      const float2 xv = *(const float2*)&inp[((size_t)src * kN + n0 + row) * 2];
      f16x8 b = {};
      if (kg == 0) { b[0] = (f16)xv.x; b[1] = (f16)xv.y; }
      Bx[pt] = b;
    }
    const f16x8* w0p = (const f16x8*)(wsW + kW0Off + (size_t)c * kW0Stride);
    const float* b0av = b0a + (size_t)bix * kH;
    const float* b0bv = b0b + (size_t)bix * kH;

    f16x8 aE, aO, aEn, aOn;
    float brE, crE, brO, crO, brEn, crEn, brOn, crOn;
    {  // prologue: mi 0,1
      const int ntE = w * 12, ntO = ntE + 1;
      aE = w0p[ntE * 64 + lane];
      aO = w0p[ntO * 64 + lane];
      const int qE = ntE * 4 + kg, qO = ntO * 4 + kg;
      brE = (qE < kH) ? b0av[qE] : 0.f;  crE = (qE < kH) ? b0bv[qE] : 0.f;
      brO = (qO < kH) ? b0av[qO] : 0.f;  crO = (qO < kH) ? b0bv[qO] : 0.f;
    }
#pragma unroll 1
    for (int it = 0; it < 6; ++it) {
      const int base = w * 12 + it * 2;
      // issue mi base+2, base+3 (it=5 lookahead lands in adjacent valid ws /
      // is q<kH-guarded for bias; never consumed)
      {
        const int ntE = base + 2, ntO = base + 3;
        aEn = w0p[ntE * 64 + lane];
        aOn = w0p[ntO * 64 + lane];
        const int qE = ntE * 4 + kg, qO = ntO * 4 + kg;
        brEn = (qE < kH) ? b0av[qE] : 0.f;  crEn = (qE < kH) ? b0bv[qE] : 0.f;
        brOn = (qO < kH) ? b0av[qO] : 0.f;  crOn = (qO < kH) ? b0bv[qO] : 0.f;
      }
      __builtin_amdgcn_sched_barrier(0);
      // consume even mi
#pragma unroll
      for (int par = 0; par < 2; ++par) {
        const f16x8 a = par ? aO : aE;
        const float br_ = par ? brO : brE, cr_ = par ? crO : crE;
        const int q = (base + par) * 4 + kg;
        f32x4 acc[4] = {};
        __builtin_amdgcn_s_setprio(1);
        acc[0] = __builtin_amdgcn_mfma_f32_16x16x32_f16(a, Bx[0], acc[0], 0, 0, 0);
        acc[1] = __builtin_amdgcn_mfma_f32_16x16x32_f16(a, Bx[1], acc[1], 0, 0, 0);
        acc[2] = __builtin_amdgcn_mfma_f32_16x16x32_f16(a, Bx[2], acc[2], 0, 0, 0);
        acc[3] = __builtin_amdgcn_mfma_f32_16x16x32_f16(a, Bx[3], acc[3], 0, 0, 0);
        __builtin_amdgcn_s_setprio(0);
#pragma unroll
        for (int pt = 0; pt < 4; ++pt) {
          const float v0 = acc[pt][0] + br_;
          const float v2 = acc[pt][2] + cr_;
          const float mag = kS2 * (v0 * v0 + v2 * v2);
          const float amp = __expf(-mag);
          const float ph  = kOmega * v0;
          f16x2 pv = {(f16)(amp * __cosf(ph)), (f16)(amp * __sinf(ph))};
          *(f16x2*)(&X[0] + xadr(l15 + 16 * pt, q * 4)) = pv;
        }
      }
      __builtin_amdgcn_sched_barrier(0);
      // rotate state (static copies; load latency already hidden)
      aE = aEn; aO = aOn;
      brE = brEn; crE = crEn; brO = brOn; crO = crOn;
    }
  }
  __syncthreads();
  const float* biasB = (const float*)(wsW + kBiasOff);
  hidden_gemm(X, (const f16x8*)(wsW + (size_t)(c * 2 + 0) * kWLayerStride),
              biasB + (size_t)(c * 2 + 0) * 192 * 4, w, lane);
  __syncthreads();
  hidden_gemm(X, (const f16x8*)(wsW + (size_t)(c * 2 + 1) * kWLayerStride),
              biasB + (size_t)(c * 2 + 1) * 192 * 4, w, lane);
  __syncthreads();
  // ---- final complex 181->3, real part; wave w owns point-tile w.
  // wf frags batch-loaded (registers free here) so the 12 loads overlap.
  {
    const f16x8* wf = (const f16x8*)(wsW + kWfOff + (size_t)c * kWfStride);
    f16x8 wfr[kKS];
#pragma unroll
    for (int ks = 0; ks < kKS; ++ks) wfr[ks] = wf[(size_t)ks * 64 + lane];
    __builtin_amdgcn_sched_barrier(0);
    f32x4 facc = {0.f, 0.f, 0.f, 0.f};
#pragma unroll
    for (int ks = 0; ks < kKS; ++ks) {
      f16x8 a = *(const f16x8*)(&X[0] + xadr(l15 + 16 * w, ks * 64 + kg * 16));
      facc = __builtin_amdgcn_mfma_f32_16x16x32_f16(a, wfr[ks], facc, 0, 0, 0);
    }
    if (l15 < kOut) {
      const float bfr = bf[(bix * kOut + l15) * 2];
#pragma unroll
      for (int j = 0; j < 4; ++j) {
        const int row = w * 16 + kg * 4 + j;
        out[((size_t)c * kN + n0 + row) * kOut + l15] = facc[j] + bfr;
      }
    }
  }
}

}  // namespace

extern "C" void kernel_launch(void* const* d_in, const int* in_sizes, int n_in,
                              void* d_out, int out_size, void* d_ws, size_t ws_size,
                              hipStream_t stream) {
  const float* inp       = (const float*)d_in[0];
  const int*   indices   = (const int*)  d_in[1];
  const int*   model_idx = (const int*)  d_in[2];
  const int*   bias_idx  = (const int*)  d_in[3];
  const float* W0a = (const float*)d_in[4];
  const float* b0a = (const float*)d_in[5];
  const float* W0b = (const float*)d_in[6];
  const float* b0b = (const float*)d_in[7];
  const float* W1a = (const float*)d_in[8];
  const float* b1a = (const float*)d_in[9];
  const float* W1b = (const float*)d_in[10];
  const float* b1b = (const float*)d_in[11];
  const float* W2a = (const float*)d_in[12];
  const float* b2a = (const float*)d_in[13];
  const float* W2b = (const float*)d_in[14];
  const float* b2b = (const float*)d_in[15];
  const float* Wf  = (const float*)d_in[16];
  const float* bff = (const float*)d_in[17];
  f16*   ws  = (f16*)d_ws;     // needs ~20.0 MB
  float* out = (float*)d_out;

  prep_hidden<<<dim3(kC * 2 * kNT), dim3(768), 0, stream>>>(
      model_idx, bias_idx, W1a, W1b, W2a, W2b, b1a, b1b, b2a, b2b, ws);
  prep_final<<<dim3(kC), dim3(768), 0, stream>>>(model_idx, Wf, ws);
  prep_l0<<<dim3(kC), dim3(256), 0, stream>>>(model_idx, W0a, W0b, ws);
  wire_main<<<dim3(kC * (kN / kMB)), dim3(256), 0, stream>>>(
      inp, indices, model_idx, bias_idx, b0a, b0b,
      bff, ws, out);
}